// Round 9
// baseline (185.104 us; speedup 1.0000x reference)
//
#include <hip/hip_runtime.h>
#include <hip/hip_bf16.h>

// Problem constants
#define Bb 2048
#define Tt 50
#define Vv 65
#define Ee 100
#define Hh 20
#define Dd 5

typedef __bf16 v8bf __attribute__((ext_vector_type(8)));
typedef short v8s __attribute__((ext_vector_type(8)));
typedef short v4s __attribute__((ext_vector_type(4)));
typedef float f32x4 __attribute__((ext_vector_type(4)));

__device__ __forceinline__ v8bf bzero8() {
    v8s z = {0, 0, 0, 0, 0, 0, 0, 0};
    union { v8s s; v8bf b; } u; u.s = z; return u.b;
}
__device__ __forceinline__ unsigned short bfbits(float f) {
    union { __hip_bfloat16 h; unsigned short s; } c;
    c.h = __float2bfloat16(f);
    return c.s;
}
__device__ __forceinline__ float bf2f(short s) {
    union { unsigned i; float f; } c; c.i = ((unsigned)(unsigned short)s) << 16; return c.f;
}
__device__ __forceinline__ unsigned pack2(float a, float b) {
    return (unsigned)bfbits(a) | ((unsigned)bfbits(b) << 16);
}

// K=16 bf16 MFMA (validated on HW in prior session)
__device__ __forceinline__ f32x4 mfma_16x16x16_bf16(v4s a, v4s b, f32x4 c) {
#if __has_builtin(__builtin_amdgcn_mfma_f32_16x16x16bf16_1k)
    return __builtin_amdgcn_mfma_f32_16x16x16bf16_1k(a, b, c, 0, 0, 0);
#else
    f32x4 d;
    asm volatile("v_mfma_f32_16x16x16_bf16 %0, %1, %2, %3\n\ts_nop 7\n\ts_nop 4"
                 : "=v"(d) : "v"(a), "v"(b), "v"(c));
    return d;
#endif
}

// ws layout (bytes)
#define WS_WKQV 1024                     // [320][128] bf16 (k rows pre-scaled by 10*log2e)
#define WS_WFF  (1024 + 81920)           // [128][128] bf16
#define WS_WLM  (1024 + 81920 + 32768)   // [80][128] bf16

#define XSTR 136                         // x/h row stride (bf16 elems)
// sh[20000] = 40.0 KB.
//  @0:      x[50][136] (6800) -> qb[20][50][8] (8000, AoS, d-pads zeroed)
//           -> lgl f32[50][68] after P3
//  @8000:   vtb[100][52] — v columns from P2; after each head's PV its 5-row
//           slice becomes that head's attn OUTPUT (attn[t][d] at [h*5+d][t])
//  @13200:  klo[1000][4] + khi[1000] @17200 — kb SoA planes
//  @13200:  h[50][136] after P3 (kb dead); tail 18200..20000 zeroed in P1;
//           h cols 100..135 of early rows read stale-but-finite kb bits against
//           zeroed Wlm cols (finite*0) — validated R7/R8.
//
// LESSONS LEDGER (R1-R8 measured):
//  - OCCUPANCY DIRECTION CLOSED: (256,4) imposes 64-arch+64-acc and this
//    kernel's live set needs ~90-110 arch -> spilled every time (R3 74MB,
//    R7 70MB, R8 35MB/dispatch). (256,3) = 170-reg cap, always spill-free.
//    Hint sets residency (3->29%, 4->37-39%, none->21.7%); resources don't.
//  - Single-pass P3 via serial shfl denominators lengthens critical path (R2).
//  - qf/kf cross-head prefetch: neutral (R6). Bulk-LDS-zero removal: good (R6).
//  - P2 j-outer + bf16-packed staging (R8): bit-identical, acc 80->16 live.
//  - THIS round: R8 structure (attp gone, rdv JIT, 1 fewer barrier) under
//    (256,3) no-spill + full P3 unroll (R1's best). Tripwire: FETCH ~1.6MB.
#define R3V 8000
#define KLO 13200
#define KHI 17200
#define HST 13200
#define VSTR 52

__global__ __launch_bounds__(256) void prep_kernel(
    const float* __restrict__ Wk, const float* __restrict__ Wq,
    const float* __restrict__ Wv, const float* __restrict__ Wff,
    const float* __restrict__ Wlm, char* __restrict__ ws,
    float* __restrict__ out)
{
    int g = blockIdx.x * 256 + threadIdx.x;
    if (g == 0) out[Bb * Tt * Vv] = 0.f;   // loss slot; gpt_main atomicAdds into it
    __hip_bfloat16* wkqv = (__hip_bfloat16*)(ws + WS_WKQV);
    __hip_bfloat16* wff  = (__hip_bfloat16*)(ws + WS_WFF);
    __hip_bfloat16* wlm  = (__hip_bfloat16*)(ws + WS_WLM);
    if (g < 40960) {
        int n = g >> 7, e = g & 127;
        float v = 0.f;
        if (e < Ee) {
            if (n < 100)      v = Wk[n * Ee + e] * 14.4269504089f; // 10 * log2(e)
            else if (n < 200) v = Wq[(n - 100) * Ee + e];
            else if (n < 300) v = Wv[(n - 200) * Ee + e];
        }
        wkqv[g] = __float2bfloat16(v);
    } else if (g < 57344) {
        int gg = g - 40960; int n = gg >> 7, e = gg & 127;
        float v = (e < Ee && n < Ee) ? Wff[n * Ee + e] : 0.f;
        wff[gg] = __float2bfloat16(v);
    } else {
        int gg = g - 57344; int n = gg >> 7, e = gg & 127;
        float v = (e < Ee && n < Vv) ? Wlm[n * Ee + e] : 0.f;
        wlm[gg] = __float2bfloat16(v);
    }
}

__global__ __launch_bounds__(256, 3) void gpt_main(
    const int* __restrict__ idx, const int* __restrict__ targets,
    const float* __restrict__ tok_emb, const float* __restrict__ pos_emb,
    const float* __restrict__ b_ff, const float* __restrict__ b_lm,
    const char* __restrict__ ws, float* __restrict__ out)
{
    __shared__ __attribute__((aligned(16))) __hip_bfloat16 sh[20000];  // 40.0 KB
    __shared__ int tok_s[Tt];
    __shared__ float bsum;

    const int b    = blockIdx.x;
    const int tid  = threadIdx.x;
    const int wave = tid >> 6;
    const int ln   = tid & 15;
    const int quad = (tid >> 4) & 3;

    // ---- P1: stage idx; fill x (cols 100..127 zeroed); zero h-tail 18200..20000 ----
    if (tid < Tt) tok_s[tid] = idx[b * Tt + tid];
    if (tid == 0) bsum = 0.f;
    {
        const uint4 z4 = make_uint4(0u, 0u, 0u, 0u);
        for (int i = tid; i < 225; i += 256) ((uint4*)&sh[18200])[i] = z4;  // 1800 elems
    }
    __syncthreads();
    for (int i = tid; i < Tt * 32; i += 256) {
        int r = i >> 5, c4 = (i & 31) * 4;
        ushort4 o;
        if (c4 < Ee) {
            const float4 te = *(const float4*)&tok_emb[tok_s[r] * Ee + c4];
            const float4 pe = *(const float4*)&pos_emb[r * Ee + c4];
            o.x = bfbits(te.x + pe.x); o.y = bfbits(te.y + pe.y);
            o.z = bfbits(te.z + pe.z); o.w = bfbits(te.w + pe.w);
        } else {
            o.x = 0; o.y = 0; o.z = 0; o.w = 0;
        }
        *(ushort4*)&sh[r * XSTR + c4] = o;
    }
    __syncthreads();

    // ---- P2: kqv = x @ Wkqv^T. j OUTER / kt inner: only acc[4] (16 regs) live
    //  during MFMA; results packed to bf16 immediately (stg[5][8] = 40 regs).
    //  Same __float2bfloat16 as a direct scatter -> bit-identical outputs. ----
    {
        const __hip_bfloat16* wkqv = (const __hip_bfloat16*)(ws + WS_WKQV);
        unsigned stg[5][8];
#pragma unroll
        for (int j = 0; j < 5; ++j) {
            f32x4 acc[4];
#pragma unroll
            for (int mt = 0; mt < 4; ++mt) {
                f32x4 z = {0.f, 0.f, 0.f, 0.f};
                acc[mt] = z;
            }
            const int nt = wave * 5 + j;
#pragma unroll
            for (int kt = 0; kt < 4; ++kt) {
                v8bf bfr = *(const v8bf*)&wkqv[(nt * 16 + ln) * 128 + kt * 32 + quad * 8];
#pragma unroll
                for (int mt = 0; mt < 4; ++mt) {
                    v8bf a = (mt < 3 || ln < 2)
                           ? *(const v8bf*)&sh[(mt * 16 + ln) * XSTR + kt * 32 + quad * 8]
                           : bzero8();
                    acc[mt] = __builtin_amdgcn_mfma_f32_16x16x32_bf16(a, bfr, acc[mt], 0, 0, 0);
                }
            }
#pragma unroll
            for (int mt = 0; mt < 4; ++mt) {
                stg[j][mt * 2]     = pack2(acc[mt][0], acc[mt][1]);
                stg[j][mt * 2 + 1] = pack2(acc[mt][2], acc[mt][3]);
            }
        }
        __syncthreads();   // all x reads done; region @0 becomes qb
        // zero qb d-pads (elements 5..7 of each 8-elem row); kb SoA has no pads
        for (int i = tid; i < 1000; i += 256) {
            *(unsigned short*)&sh[i * 8 + 5] = 0;
            *(unsigned*)&sh[i * 8 + 6] = 0;
        }
        // scatter staged bf16 bits; C/D map: col(n)=ln, row(m)=quad*4+r
#pragma unroll
        for (int j = 0; j < 5; ++j) {
            int n = (wave * 5 + j) * 16 + ln;
            if (n < 300) {
                int mat = n / 100;
                int jj  = n - mat * 100;
                int h   = jj / 5, d = jj - (jj / 5) * 5;
                if (mat == 2) {
                    // vtb: vectorized conflict-free stores, stride 52
                    int base = R3V + (h * 5 + d) * VSTR;
#pragma unroll
                    for (int mt = 0; mt < 4; ++mt) {
                        if (mt < 3 || quad == 0) {   // mt==3,quad>0 would spill past row end
                            unsigned w0 = stg[j][mt * 2];
                            unsigned w1 = (mt == 3) ? 0u : stg[j][mt * 2 + 1];  // t=50,51 stay zero
                            *(uint2*)&sh[base + mt * 16 + quad * 4] = make_uint2(w0, w1);
                        }
                    }
                } else if (mat == 1) {   // qb AoS @0
                    int rbase = h * 50;
#pragma unroll
                    for (int mt = 0; mt < 4; ++mt)
#pragma unroll
                        for (int r = 0; r < 4; ++r) {
                            int m = mt * 16 + quad * 4 + r;
                            if (m < Tt) {
                                unsigned w = stg[j][mt * 2 + (r >> 1)];
                                *(unsigned short*)&sh[(rbase + m) * 8 + d] =
                                    (unsigned short)((r & 1) ? (w >> 16) : (w & 0xffff));
                            }
                        }
                } else {                 // kb SoA planes
                    int rbase = h * 50;
#pragma unroll
                    for (int mt = 0; mt < 4; ++mt)
#pragma unroll
                        for (int r = 0; r < 4; ++r) {
                            int m = mt * 16 + quad * 4 + r;
                            if (m < Tt) {
                                unsigned w = stg[j][mt * 2 + (r >> 1)];
                                unsigned short v =
                                    (unsigned short)((r & 1) ? (w >> 16) : (w & 0xffff));
                                if (d < 4) *(unsigned short*)&sh[KLO + (rbase + m) * 4 + d] = v;
                                else       *(unsigned short*)&sh[KHI + rbase + m] = v;
                            }
                        }
                }
            }
        }
    }
    __syncthreads();

    // ---- P3: attention, dual-orientation (R1 structure), rdv JIT per s-tile,
    //  per-head attn dump into the head's dead vtb slice. Full unroll (R1's
    //  best config — (256,3)'s 170-reg budget holds one-pass liveness). ----
    {
        const float BIGF = 3.0e38f;
        float dA2[4], dA1[4], d50[4];
#pragma unroll
        for (int r = 0; r < 4; ++r) {
            int qr = quad * 4 + r;
            dA2[r] = (qr >= ln) ? BIGF : 0.f;   // orient-2 diag tiles: t>=s
            dA1[r] = (ln >= qr) ? BIGF : 0.f;   // orient-1 diag tiles (u==0): t>=s
            d50[r] = (qr < 2)  ? BIGF : 0.f;    // tile-3 reg mask: (48+qr)<50
        }
        const float tl3 = (ln < 2) ? BIGF : 0.f;  // orient-1 t-tile 3: t=48+ln<50

        v4s ones4; ones4[0] = ones4[1] = ones4[2] = ones4[3] = (short)0x3F80; // bf16 1.0

#pragma unroll
        for (int hj = 0; hj < 5; ++hj) {
            const int h = wave * 5 + hj;
            v8bf qf[4], kf[4];
#pragma unroll
            for (int i = 0; i < 4; ++i) {
                int row = h * 50 + i * 16 + ln;
                if (quad == 0) {
                    qf[i] = *(const v8bf*)&sh[row * 8];
                    union { unsigned long long u[2]; v8bf b; } uk;
                    uk.u[0] = *(const unsigned long long*)&sh[KLO + row * 4];
                    uk.u[1] = (unsigned long long)*(const unsigned short*)&sh[KHI + row];
                    kf[i] = uk.b;   // d5..7 implicitly zero
                } else {
                    qf[i] = bzero8(); kf[i] = bzero8();
                }
            }
            f32x4 pac[4];
#pragma unroll
            for (int mt = 0; mt < 4; ++mt) { f32x4 z = {0.f, 0.f, 0.f, 0.f}; pac[mt] = z; }
#pragma unroll
            for (int ms = 0; ms < 4; ++ms) {
                // --- denominators for s-tile ms (orient-2: D2[t][s], t=quad*4+r, s=ln) ---
                float esum[4] = {0.f, 0.f, 0.f, 0.f};
#pragma unroll
                for (int mt = ms; mt < 4; ++mt) {
                    f32x4 z = {0.f, 0.f, 0.f, 0.f};
                    f32x4 t2 = __builtin_amdgcn_mfma_f32_16x16x32_bf16(kf[mt], qf[ms], z, 0, 0, 0);
#pragma unroll
                    for (int r = 0; r < 4; ++r) {
                        float x = __builtin_amdgcn_exp2f(t2[r]);
                        if (mt == ms) x = fminf(x, dA2[r]);   // causal mask, diag tile only
                        if (mt == 3)  x = fminf(x, d50[r]);   // t<50, last t-tile only
                        esum[r] += x;
                    }
                }
                v4s af0;
                af0[0] = (short)bfbits(esum[0]); af0[1] = (short)bfbits(esum[1]);
                af0[2] = (short)bfbits(esum[2]); af0[3] = (short)bfbits(esum[3]);
                f32x4 z0 = {0.f, 0.f, 0.f, 0.f};
                f32x4 dres = mfma_16x16x16_bf16(af0, ones4, z0);
                float rdv[4];
#pragma unroll
                for (int r = 0; r < 4; ++r)
                    rdv[r] = (ms < 3 || (quad * 4 + r) < 2)   // s<50 guard (select: NaN-proof)
                           ? __builtin_amdgcn_rcpf(dres[r]) : 0.f;
                // --- v column with 1/denom folded in ---
                v4s braw;
                if (ln < Dd && (ms < 3 || quad == 0))
                    braw = *(const v4s*)&sh[R3V + (h * 5 + ln) * VSTR + ms * 16 + quad * 4];
                else { v4s zz = {0, 0, 0, 0}; braw = zz; }
                v4s bvt;
#pragma unroll
                for (int j = 0; j < 4; ++j)
                    bvt[j] = (short)bfbits(bf2f(braw[j]) * rdv[j]);
                // --- PV for s-tile ms (orient-1: D1[s][t] -> masked exp = A-frag) ---
#pragma unroll
                for (int u = 0; u < 4 - ms; ++u) {
                    f32x4 z = {0.f, 0.f, 0.f, 0.f};
                    f32x4 t1 = __builtin_amdgcn_mfma_f32_16x16x32_bf16(qf[ms], kf[ms + u], z, 0, 0, 0);
                    v4s af;
#pragma unroll
                    for (int r = 0; r < 4; ++r) {
                        float x = __builtin_amdgcn_exp2f(t1[r]);
                        if (u == 0)      x = fminf(x, dA1[r]);   // causal mask, diag tile
                        if (ms + u == 3) x = fminf(x, tl3);      // t<50, last t-tile
                        if (ms == 3)     x = fminf(x, d50[r]);   // s<50, last s-tile
                        af[r] = (short)bfbits(x);
                    }
                    pac[ms + u] = mfma_16x16x16_bf16(af, bvt, pac[ms + u]);
                }
            }
            // --- dump this head's attn into its (now dead) vtb slice:
            //     attn[t][d] -> sh[R3V + (h*5+d)*52 + t]; slots 50,51 stay zero ---
            if (ln < Dd) {
                int base = R3V + (h * 5 + ln) * VSTR;
#pragma unroll
                for (int mt = 0; mt < 3; ++mt) {
                    *(unsigned*)&sh[base + mt * 16 + quad * 4]     = pack2(pac[mt][0], pac[mt][1]);
                    *(unsigned*)&sh[base + mt * 16 + quad * 4 + 2] = pack2(pac[mt][2], pac[mt][3]);
                }
                if (quad == 0)   // t=48,49 only; never touch pad slots 50,51
                    *(unsigned*)&sh[base + 48] = pack2(pac[3][0], pac[3][1]);
            }
        }
    }
    __syncthreads();   // all qb/kb/vtb reads + attn dumps done

    // ---- P4: h = relu(attn @ Wff^T + b_ff); attn read transposed from vtb ----
    {
        const __hip_bfloat16* wff = (const __hip_bfloat16*)(ws + WS_WFF);
        f32x4 fac[2][4];
#pragma unroll
        for (int u = 0; u < 2; ++u)
#pragma unroll
            for (int mt = 0; mt < 4; ++mt) {
                f32x4 z = {0.f, 0.f, 0.f, 0.f};
                fac[u][mt] = z;
            }
        const int nn = (wave < 3) ? 2 : 1;
#pragma unroll
        for (int kt = 0; kt < 4; ++kt) {
            v8bf a[4];
#pragma unroll
            for (int mt = 0; mt < 4; ++mt) {
                const int m = mt * 16 + ln;
                const bool rowok = (mt < 3) || (ln < 2);
                const int c0 = kt * 32 + quad * 8;
                union { unsigned short u[8]; v8bf b; } ua;
#pragma unroll
                for (int e = 0; e < 8; ++e) {
                    int c = c0 + e;   // vtb row index == flat head*5+d == column c
                    ua.u[e] = (rowok && c < Ee)
                            ? *(const unsigned short*)&sh[R3V + c * VSTR + m]
                            : (unsigned short)0;
                }
                a[mt] = ua.b;
            }
#pragma unroll
            for (int u = 0; u < 2; ++u) {
                if (u < nn) {
                    int nt = wave + u * 4;
                    v8bf bfr = *(const v8bf*)&wff[(nt * 16 + ln) * 128 + kt * 32 + quad * 8];
#pragma unroll
                    for (int mt = 0; mt < 4; ++mt)
                        fac[u][mt] = __builtin_amdgcn_mfma_f32_16x16x32_bf16(a[mt], bfr, fac[u][mt], 0, 0, 0);
                }
            }
        }
#pragma unroll
        for (int u = 0; u < 2; ++u) {
            if (u < nn) {
                int n = (wave + u * 4) * 16 + ln;
                if (n < Ee) {
                    float bias = b_ff[n];
#pragma unroll
                    for (int mt = 0; mt < 4; ++mt)
#pragma unroll
                        for (int r = 0; r < 4; ++r) {
                            int m = mt * 16 + quad * 4 + r;
                            if (m < Tt) {
                                float v = fac[u][mt][r] + bias;
                                sh[HST + m * XSTR + n] = __float2bfloat16(v > 0.f ? v : 0.f);
                            }
                        }
                }
            }
        }
    }
    __syncthreads();

    // ---- P5: logits = h @ Wlm^T + b_lm; h(@HST) -> out + logits f32(@0) ----
    {
        const __hip_bfloat16* wlm = (const __hip_bfloat16*)(ws + WS_WLM);
        float* lgl = (float*)sh;   // [50][68] f32 = 13600B (qb dead)
#pragma unroll
        for (int i = 0; i < 5; ++i) {
            int job = wave + i * 4;            // 0..19
            int mt = job / 5, nt = job - (job / 5) * 5;
            f32x4 acc = {0.f, 0.f, 0.f, 0.f};
#pragma unroll
            for (int kt = 0; kt < 4; ++kt) {
                v8bf a = (mt < 3 || ln < 2)
                       ? *(const v8bf*)&sh[HST + (mt * 16 + ln) * XSTR + kt * 32 + quad * 8]
                       : bzero8();
                v8bf bf = *(const v8bf*)&wlm[(nt * 16 + ln) * 128 + kt * 32 + quad * 8];
                acc = __builtin_amdgcn_mfma_f32_16x16x32_bf16(a, bf, acc, 0, 0, 0);
            }
            int n = nt * 16 + ln;
            if (n < Vv) {
                float bias = b_lm[n];
#pragma unroll
                for (int r = 0; r < 4; ++r) {
                    int m = mt * 16 + quad * 4 + r;
                    if (m < Tt) {
                        float v = acc[r] + bias;
                        out[(b * Tt + m) * Vv + n] = v;
                        lgl[m * 68 + n] = v;
                    }
                }
            }
        }
    }
    __syncthreads();

    // ---- P6: loss; 4 lanes per token row; one device atomic per block ----
    if (tid < 200) {
        int r = tid >> 2, lv = tid & 3;
        const float* row = (const float*)sh + r * 68;
        float mx = -3.0e38f;
        for (int v = lv; v < Vv; v += 4) mx = fmaxf(mx, row[v]);
        mx = fmaxf(mx, __shfl_xor(mx, 1));
        mx = fmaxf(mx, __shfl_xor(mx, 2));
        float sum = 0.f;
        for (int v = lv; v < Vv; v += 4)
            sum += __builtin_amdgcn_exp2f((row[v] - mx) * 1.4426950408889634f);
        sum += __shfl_xor(sum, 1);
        sum += __shfl_xor(sum, 2);
        if (lv == 0) {
            float lse = mx + 0.69314718055994531f * log2f(sum);
            int tgt = targets[b * Tt + r];
            atomicAdd(&bsum, lse - row[tgt]);
        }
    }
    __syncthreads();
    if (tid == 0)
        atomicAdd(&out[Bb * Tt * Vv], bsum * (1.0f / (float)(Bb * Tt)));
}

extern "C" void kernel_launch(void* const* d_in, const int* in_sizes, int n_in,
                              void* d_out, int out_size, void* d_ws, size_t ws_size,
                              hipStream_t stream)
{
    const int* idx     = (const int*)d_in[0];
    const int* targets = (const int*)d_in[1];
    const float* tok_emb = (const float*)d_in[2];
    const float* pos_emb = (const float*)d_in[3];
    const float* Wk  = (const float*)d_in[4];
    const float* Wq  = (const float*)d_in[5];
    const float* Wv  = (const float*)d_in[6];
    const float* Wff = (const float*)d_in[7];
    const float* bff = (const float*)d_in[8];
    const float* Wlm = (const float*)d_in[9];
    const float* blm = (const float*)d_in[10];
    float* out = (float*)d_out;
    char* ws = (char*)d_ws;

    hipLaunchKernelGGL(prep_kernel, dim3(264), dim3(256), 0, stream, Wk, Wq, Wv, Wff, Wlm, ws, out);
    hipLaunchKernelGGL(gpt_main, dim3(Bb), dim3(256), 0, stream,
                       idx, targets, tok_emb, pos_emb, bff, blm, (const char*)ws, out);
}

// Round 10
// 174.637 us; speedup vs baseline: 1.0599x; 1.0599x over previous
//
#include <hip/hip_runtime.h>
#include <hip/hip_bf16.h>

// Problem constants
#define Bb 2048
#define Tt 50
#define Vv 65
#define Ee 100
#define Hh 20
#define Dd 5

typedef __bf16 v8bf __attribute__((ext_vector_type(8)));
typedef short v8s __attribute__((ext_vector_type(8)));
typedef short v4s __attribute__((ext_vector_type(4)));
typedef float f32x4 __attribute__((ext_vector_type(4)));

__device__ __forceinline__ v8bf bzero8() {
    v8s z = {0, 0, 0, 0, 0, 0, 0, 0};
    union { v8s s; v8bf b; } u; u.s = z; return u.b;
}
__device__ __forceinline__ unsigned short bfbits(float f) {
    union { __hip_bfloat16 h; unsigned short s; } c;
    c.h = __float2bfloat16(f);
    return c.s;
}
__device__ __forceinline__ float bf2f(short s) {
    union { unsigned i; float f; } c; c.i = ((unsigned)(unsigned short)s) << 16; return c.f;
}
__device__ __forceinline__ unsigned pack2(float a, float b) {
    return (unsigned)bfbits(a) | ((unsigned)bfbits(b) << 16);
}

// K=16 bf16 MFMA (validated on HW in prior session)
__device__ __forceinline__ f32x4 mfma_16x16x16_bf16(v4s a, v4s b, f32x4 c) {
#if __has_builtin(__builtin_amdgcn_mfma_f32_16x16x16bf16_1k)
    return __builtin_amdgcn_mfma_f32_16x16x16bf16_1k(a, b, c, 0, 0, 0);
#else
    f32x4 d;
    asm volatile("v_mfma_f32_16x16x16_bf16 %0, %1, %2, %3\n\ts_nop 7\n\ts_nop 4"
                 : "=v"(d) : "v"(a), "v"(b), "v"(c));
    return d;
#endif
}

// ws layout (bytes)
#define WS_WKQV 1024                     // [320][128] bf16 (k rows pre-scaled by 10*log2e)
#define WS_WFF  (1024 + 81920)           // [128][128] bf16
#define WS_WLM  (1024 + 81920 + 32768)   // [80][128] bf16

#define XSTR 136                         // x/attn/h row stride (bf16 elems)
// shared overlays (bf16 element offsets into sh[21200] = 42.4 KB, 3 blocks/CU):
//  region1 @0     (8000): x[50][136] -> qb[20][50][8] -> attnbuf[50][136] -> lgl f32[50][68]
//  region2 @8000  (8000): kb[20][50][8] -> h[50][136]
//  region3 @16000 (5200): vtb[20][5][52]
// No bulk zeroing: weight pad COLUMNS (e>=100) are zeroed in prep, so finite
// garbage in A-pads multiplies 0.0. NaN sources cleared: x cols 100..127 in
// fill loop; qb AND kb d-pads in P2 pad-zero loop; vtb fully overwritten.
//
// LESSONS LEDGER (R1-R9 measured):
//  - (256,3) is the ONLY good launch bound: 170-reg cap, never spilled.
//    (256,4) = 64arch+64acc budget -> spilled every attempt (R3/R7/R8, 20-74MB
//    per dispatch). No hint -> VGPR 100, occ 21.7%, slowest. Occupancy tracks
//    the hint (3->29%, 4->38%), not resources. DIRECTION CLOSED.
//  - Single-pass P3 (serial shfl denominators): critical path grows, loses (R2).
//  - SoA q/k + 30.4KB LDS: no occupancy change, +assembly VALU (R4). AoS kept.
//  - attn->vtb dump + P4 scalar transposed reads: -8.5us vs R6 (R9). attnbuf
//    dump + vector P4 reads kept.
//  - Cross-head qf/kf prefetch: neutral (R6). Dropped here.
//  - THIS round: R6-exact + batched MFMA issue in P3 (t2s[10] up-front;
//    t1s[4] per ms) — pure reorder, bit-identical math, frees the scheduler
//    to overlap MFMA bursts of one wave with VALU bursts of others (m114).
//    Spill tripwire: FETCH ~1.55MB / WRITE ~26.1MB.
#define R2 8000
#define R3 16000
#define VSTR 52

__global__ __launch_bounds__(256) void prep_kernel(
    const float* __restrict__ Wk, const float* __restrict__ Wq,
    const float* __restrict__ Wv, const float* __restrict__ Wff,
    const float* __restrict__ Wlm, char* __restrict__ ws,
    float* __restrict__ out)
{
    int g = blockIdx.x * 256 + threadIdx.x;
    if (g == 0) out[Bb * Tt * Vv] = 0.f;   // loss slot; gpt_main atomicAdds into it
    __hip_bfloat16* wkqv = (__hip_bfloat16*)(ws + WS_WKQV);
    __hip_bfloat16* wff  = (__hip_bfloat16*)(ws + WS_WFF);
    __hip_bfloat16* wlm  = (__hip_bfloat16*)(ws + WS_WLM);
    if (g < 40960) {
        int n = g >> 7, e = g & 127;
        float v = 0.f;
        if (e < Ee) {
            if (n < 100)      v = Wk[n * Ee + e] * 14.4269504089f; // 10 * log2(e)
            else if (n < 200) v = Wq[(n - 100) * Ee + e];
            else if (n < 300) v = Wv[(n - 200) * Ee + e];
        }
        wkqv[g] = __float2bfloat16(v);
    } else if (g < 57344) {
        int gg = g - 40960; int n = gg >> 7, e = gg & 127;
        float v = (e < Ee && n < Ee) ? Wff[n * Ee + e] : 0.f;
        wff[gg] = __float2bfloat16(v);
    } else {
        int gg = g - 57344; int n = gg >> 7, e = gg & 127;
        float v = (e < Ee && n < Vv) ? Wlm[n * Ee + e] : 0.f;
        wlm[gg] = __float2bfloat16(v);
    }
}

__global__ __launch_bounds__(256, 3) void gpt_main(
    const int* __restrict__ idx, const int* __restrict__ targets,
    const float* __restrict__ tok_emb, const float* __restrict__ pos_emb,
    const float* __restrict__ b_ff, const float* __restrict__ b_lm,
    const char* __restrict__ ws, float* __restrict__ out)
{
    __shared__ __attribute__((aligned(16))) __hip_bfloat16 sh[21200];  // 42.4 KB
    __shared__ int tok_s[Tt];
    __shared__ float bsum;

    const int b    = blockIdx.x;
    const int tid  = threadIdx.x;
    const int wave = tid >> 6;
    const int ln   = tid & 15;
    const int quad = (tid >> 4) & 3;

    // ---- P1: stage idx; fill x = tok_emb[idx]+pos_emb (cols 100..127 zeroed) ----
    if (tid < Tt) tok_s[tid] = idx[b * Tt + tid];
    if (tid == 0) bsum = 0.f;
    __syncthreads();
    for (int i = tid; i < Tt * 32; i += 256) {
        int r = i >> 5, c4 = (i & 31) * 4;
        ushort4 o;
        if (c4 < Ee) {
            const float4 te = *(const float4*)&tok_emb[tok_s[r] * Ee + c4];
            const float4 pe = *(const float4*)&pos_emb[r * Ee + c4];
            o.x = bfbits(te.x + pe.x); o.y = bfbits(te.y + pe.y);
            o.z = bfbits(te.z + pe.z); o.w = bfbits(te.w + pe.w);
        } else {
            o.x = 0; o.y = 0; o.z = 0; o.w = 0;
        }
        *(ushort4*)&sh[r * XSTR + c4] = o;
    }
    __syncthreads();

    // ---- P2: kqv = x @ Wkqv^T via MFMA (4 waves x 5 n-tiles x 4 m-tiles) ----
    {
        const __hip_bfloat16* wkqv = (const __hip_bfloat16*)(ws + WS_WKQV);
        f32x4 acc[5][4];
#pragma unroll
        for (int j = 0; j < 5; ++j)
#pragma unroll
            for (int mt = 0; mt < 4; ++mt) {
                f32x4 z = {0.f, 0.f, 0.f, 0.f};
                acc[j][mt] = z;
            }
#pragma unroll
        for (int kt = 0; kt < 4; ++kt) {
            v8bf a[4];
#pragma unroll
            for (int mt = 0; mt < 4; ++mt)
                a[mt] = (mt < 3 || ln < 2)
                      ? *(const v8bf*)&sh[(mt * 16 + ln) * XSTR + kt * 32 + quad * 8]
                      : bzero8();
#pragma unroll
            for (int j = 0; j < 5; ++j) {
                int nt = wave * 5 + j;
                v8bf bfr = *(const v8bf*)&wkqv[(nt * 16 + ln) * 128 + kt * 32 + quad * 8];
#pragma unroll
                for (int mt = 0; mt < 4; ++mt)
                    acc[j][mt] = __builtin_amdgcn_mfma_f32_16x16x32_bf16(a[mt], bfr, acc[j][mt], 0, 0, 0);
            }
        }
        __syncthreads();   // all x reads done; region1 becomes qb
        // zero qb AND kb d-pads (elements 5..7 of each 8-elem row)
        for (int i = tid; i < 2000; i += 256) {
            int off = (i < 1000) ? i * 8 : R2 + (i - 1000) * 8;
            *(unsigned short*)&sh[off + 5] = 0;
            *(unsigned*)&sh[off + 6] = 0;
        }
        // C/D: col(n)=ln, row(m)=quad*4+r
#pragma unroll
        for (int j = 0; j < 5; ++j) {
            int n = (wave * 5 + j) * 16 + ln;
            if (n < 300) {
                int mat = n / 100;
                int jj  = n - mat * 100;
                int h   = jj / 5, d = jj - (jj / 5) * 5;
                if (mat == 2) {
                    // vtb: vectorized conflict-free stores, stride 52
                    int base = R3 + (h * 5 + d) * VSTR;
#pragma unroll
                    for (int mt = 0; mt < 4; ++mt) {
                        if (mt < 3 || quad == 0) {   // mt==3,quad>0 would spill past row end
                            float v0 = acc[j][mt][0], v1 = acc[j][mt][1];
                            float v2 = acc[j][mt][2], v3 = acc[j][mt][3];
                            if (mt == 3) { v2 = 0.f; v3 = 0.f; }   // t=50,51 pad slots stay zero
                            uint2 pk = make_uint2(pack2(v0, v1), pack2(v2, v3));
                            *(uint2*)&sh[base + mt * 16 + quad * 4] = pk;
                        }
                    }
                } else {
                    int roff = (mat == 0) ? R2 : 0;   // kb -> region2, qb -> region1
                    int rbase = h * 50;
#pragma unroll
                    for (int mt = 0; mt < 4; ++mt)
#pragma unroll
                        for (int r = 0; r < 4; ++r) {
                            int m = mt * 16 + quad * 4 + r;
                            if (m < Tt)
                                sh[roff + (rbase + m) * 8 + d] = __float2bfloat16(acc[j][mt][r]);
                        }
                }
            }
        }
    }
    __syncthreads();

    // ---- P3: attention, dual-orientation (R1/R6 structure) with BATCHED MFMA
    //  issue: all 10 orient-2 QK tiles computed up-front (t2s burst), then the
    //  exp/esum/ones-MFMA per ns; orient-1 t1 tiles batched per ms. Pure
    //  reorder of independent ops — bit-identical results. ----
    unsigned attp[5][8];
    {
        const float BIGF = 3.0e38f;
        float dA2[4], dA1[4], d50[4];
#pragma unroll
        for (int r = 0; r < 4; ++r) {
            int qr = quad * 4 + r;
            dA2[r] = (qr >= ln) ? BIGF : 0.f;   // orient-2 diag tiles: t>=s
            dA1[r] = (ln >= qr) ? BIGF : 0.f;   // orient-1 diag tiles (u==0): t>=s
            d50[r] = (qr < 2)  ? BIGF : 0.f;    // tile-3 reg mask: (48+qr)<50
        }
        const float tl3 = (ln < 2) ? BIGF : 0.f;  // orient-1 t-tile 3: t=48+ln<50

        v4s ones4; ones4[0] = ones4[1] = ones4[2] = ones4[3] = (short)0x3F80; // bf16 1.0

#pragma unroll
        for (int hj = 0; hj < 5; ++hj) {
            const int h = wave * 5 + hj;
            v8bf qf[4], kf[4];
#pragma unroll
            for (int i = 0; i < 4; ++i) {
                int row = (h * 50 + i * 16 + ln) * 8;
                qf[i] = (quad == 0) ? *(const v8bf*)&sh[row] : bzero8();
                kf[i] = (quad == 0) ? *(const v8bf*)&sh[R2 + row] : bzero8();
            }
            // --- orient-2 QK burst: 10 independent MFMAs (ns,mt>=ns) ---
            f32x4 t2s[10];
            {
                int idx = 0;
#pragma unroll
                for (int ns = 0; ns < 4; ++ns)
#pragma unroll
                    for (int mt = 0; mt < 4; ++mt)
                        if (mt >= ns) {
                            f32x4 z = {0.f, 0.f, 0.f, 0.f};
                            t2s[idx++] = __builtin_amdgcn_mfma_f32_16x16x32_bf16(kf[mt], qf[ns], z, 0, 0, 0);
                        }
            }
            // --- denominators per s-tile: exp burst -> esum -> ones-MFMA -> rcp ---
            float rdv[4][4];
            {
                int idx = 0;
#pragma unroll
                for (int ns = 0; ns < 4; ++ns) {
                    float esum[4] = {0.f, 0.f, 0.f, 0.f};
#pragma unroll
                    for (int mt = 0; mt < 4; ++mt)
                        if (mt >= ns) {
                            f32x4 t2 = t2s[idx++];
#pragma unroll
                            for (int r = 0; r < 4; ++r) {
                                float x = __builtin_amdgcn_exp2f(t2[r]);
                                if (mt == ns) x = fminf(x, dA2[r]);   // causal mask, diag tile
                                if (mt == 3)  x = fminf(x, d50[r]);   // t<50, last t-tile
                                esum[r] += x;
                            }
                        }
                    v4s af0;
                    af0[0] = (short)bfbits(esum[0]); af0[1] = (short)bfbits(esum[1]);
                    af0[2] = (short)bfbits(esum[2]); af0[3] = (short)bfbits(esum[3]);
                    f32x4 z0 = {0.f, 0.f, 0.f, 0.f};
                    f32x4 dres = mfma_16x16x16_bf16(af0, ones4, z0);
#pragma unroll
                    for (int r = 0; r < 4; ++r)
                        rdv[ns][r] = (ns < 3 || (quad * 4 + r) < 2)   // s<50 guard (select: NaN-proof)
                                   ? __builtin_amdgcn_rcpf(dres[r]) : 0.f;
                }
            }
            // --- PV (orient-1), t1 batched within each ms ---
            f32x4 pac[4];
#pragma unroll
            for (int mt = 0; mt < 4; ++mt) { f32x4 z = {0.f, 0.f, 0.f, 0.f}; pac[mt] = z; }
#pragma unroll
            for (int ms = 0; ms < 4; ++ms) {
                v4s braw;
                if (ln < Dd && (ms < 3 || quad == 0))
                    braw = *(const v4s*)&sh[R3 + (h * 5 + ln) * VSTR + ms * 16 + quad * 4];
                else { v4s zz = {0, 0, 0, 0}; braw = zz; }
                v4s bvt;
#pragma unroll
                for (int j = 0; j < 4; ++j)
                    bvt[j] = (short)bfbits(bf2f(braw[j]) * rdv[ms][j]);
                // t1 burst: independent MFMAs for u = 0..3-ms
                f32x4 t1s[4];
#pragma unroll
                for (int u = 0; u < 4; ++u)
                    if (u < 4 - ms) {
                        f32x4 z = {0.f, 0.f, 0.f, 0.f};
                        t1s[u] = __builtin_amdgcn_mfma_f32_16x16x32_bf16(qf[ms], kf[ms + u], z, 0, 0, 0);
                    }
#pragma unroll
                for (int u = 0; u < 4; ++u)
                    if (u < 4 - ms) {
                        v4s af;
#pragma unroll
                        for (int r = 0; r < 4; ++r) {
                            float x = __builtin_amdgcn_exp2f(t1s[u][r]);
                            if (u == 0)      x = fminf(x, dA1[r]);   // causal mask, diag tile
                            if (ms + u == 3) x = fminf(x, tl3);      // t<50, last t-tile
                            if (ms == 3)     x = fminf(x, d50[r]);   // s<50, last s-tile
                            af[r] = (short)bfbits(x);
                        }
                        pac[ms + u] = mfma_16x16x16_bf16(af, bvt, pac[ms + u]);
                    }
            }
            // C/D of 16x16x16: col n=ln (d), row m=quad*4+r -> t = mt*16+quad*4+r
#pragma unroll
            for (int mt = 0; mt < 4; ++mt) {
                attp[hj][mt * 2]     = pack2(pac[mt][0], pac[mt][1]);
                attp[hj][mt * 2 + 1] = pack2(pac[mt][2], pac[mt][3]);
            }
        }
    }
    __syncthreads();   // all qb/kb/vtb reads done; region1 becomes attnbuf

    // ---- dump attn registers -> attnbuf (region1, [50][136]) ----
#pragma unroll
    for (int hj = 0; hj < 5; ++hj) {
        int col = (wave * 5 + hj) * 5 + ln;
#pragma unroll
        for (int mt = 0; mt < 4; ++mt)
#pragma unroll
            for (int r = 0; r < 4; ++r) {
                int t = mt * 16 + quad * 4 + r;
                if (ln < Dd && t < Tt) {
                    unsigned w = attp[hj][mt * 2 + (r >> 1)];
                    unsigned short v = (unsigned short)((r & 1) ? (w >> 16) : (w & 0xffff));
                    *(unsigned short*)&sh[t * XSTR + col] = v;
                }
            }
    }
    __syncthreads();

    // ---- P4: h = relu(attn @ Wff^T + b_ff); attnbuf(region1) -> h(region2) ----
    {
        const __hip_bfloat16* wff = (const __hip_bfloat16*)(ws + WS_WFF);
        f32x4 fac[2][4];
#pragma unroll
        for (int u = 0; u < 2; ++u)
#pragma unroll
            for (int mt = 0; mt < 4; ++mt) {
                f32x4 z = {0.f, 0.f, 0.f, 0.f};
                fac[u][mt] = z;
            }
        const int nn = (wave < 3) ? 2 : 1;
#pragma unroll
        for (int kt = 0; kt < 4; ++kt) {
            v8bf a[4];
#pragma unroll
            for (int mt = 0; mt < 4; ++mt)
                a[mt] = (mt < 3 || ln < 2)
                      ? *(const v8bf*)&sh[(mt * 16 + ln) * XSTR + kt * 32 + quad * 8]
                      : bzero8();
#pragma unroll
            for (int u = 0; u < 2; ++u) {
                if (u < nn) {
                    int nt = wave + u * 4;
                    v8bf bfr = *(const v8bf*)&wff[(nt * 16 + ln) * 128 + kt * 32 + quad * 8];
#pragma unroll
                    for (int mt = 0; mt < 4; ++mt)
                        fac[u][mt] = __builtin_amdgcn_mfma_f32_16x16x32_bf16(a[mt], bfr, fac[u][mt], 0, 0, 0);
                }
            }
        }
#pragma unroll
        for (int u = 0; u < 2; ++u) {
            if (u < nn) {
                int n = (wave + u * 4) * 16 + ln;
                if (n < Ee) {
                    float bias = b_ff[n];
#pragma unroll
                    for (int mt = 0; mt < 4; ++mt)
#pragma unroll
                        for (int r = 0; r < 4; ++r) {
                            int m = mt * 16 + quad * 4 + r;
                            if (m < Tt) {
                                float v = fac[u][mt][r] + bias;
                                sh[R2 + m * XSTR + n] = __float2bfloat16(v > 0.f ? v : 0.f);
                            }
                        }
                }
            }
        }
    }
    __syncthreads();

    // ---- P5: logits = h @ Wlm^T + b_lm; h(region2) -> out + logits f32(region1) ----
    {
        const __hip_bfloat16* wlm = (const __hip_bfloat16*)(ws + WS_WLM);
        float* lgl = (float*)sh;   // [50][68] f32 = 13600B
#pragma unroll
        for (int i = 0; i < 5; ++i) {
            int job = wave + i * 4;            // 0..19
            int mt = job / 5, nt = job - (job / 5) * 5;
            f32x4 acc = {0.f, 0.f, 0.f, 0.f};
#pragma unroll
            for (int kt = 0; kt < 4; ++kt) {
                v8bf a = (mt < 3 || ln < 2)
                       ? *(const v8bf*)&sh[R2 + (mt * 16 + ln) * XSTR + kt * 32 + quad * 8]
                       : bzero8();
                v8bf bf = *(const v8bf*)&wlm[(nt * 16 + ln) * 128 + kt * 32 + quad * 8];
                acc = __builtin_amdgcn_mfma_f32_16x16x32_bf16(a, bf, acc, 0, 0, 0);
            }
            int n = nt * 16 + ln;
            if (n < Vv) {
                float bias = b_lm[n];
#pragma unroll
                for (int r = 0; r < 4; ++r) {
                    int m = mt * 16 + quad * 4 + r;
                    if (m < Tt) {
                        float v = acc[r] + bias;
                        out[(b * Tt + m) * Vv + n] = v;
                        lgl[m * 68 + n] = v;
                    }
                }
            }
        }
    }
    __syncthreads();

    // ---- P6: loss; 4 lanes per token row; one device atomic per block ----
    if (tid < 200) {
        int r = tid >> 2, lv = tid & 3;
        const float* row = (const float*)sh + r * 68;
        float mx = -3.0e38f;
        for (int v = lv; v < Vv; v += 4) mx = fmaxf(mx, row[v]);
        mx = fmaxf(mx, __shfl_xor(mx, 1));
        mx = fmaxf(mx, __shfl_xor(mx, 2));
        float sum = 0.f;
        for (int v = lv; v < Vv; v += 4)
            sum += __builtin_amdgcn_exp2f((row[v] - mx) * 1.4426950408889634f);
        sum += __shfl_xor(sum, 1);
        sum += __shfl_xor(sum, 2);
        if (lv == 0) {
            float lse = mx + 0.69314718055994531f * log2f(sum);
            int tgt = targets[b * Tt + r];
            atomicAdd(&bsum, lse - row[tgt]);
        }
    }
    __syncthreads();
    if (tid == 0)
        atomicAdd(&out[Bb * Tt * Vv], bsum * (1.0f / (float)(Bb * Tt)));
}

extern "C" void kernel_launch(void* const* d_in, const int* in_sizes, int n_in,
                              void* d_out, int out_size, void* d_ws, size_t ws_size,
                              hipStream_t stream)
{
    const int* idx     = (const int*)d_in[0];
    const int* targets = (const int*)d_in[1];
    const float* tok_emb = (const float*)d_in[2];
    const float* pos_emb = (const float*)d_in[3];
    const float* Wk  = (const float*)d_in[4];
    const float* Wq  = (const float*)d_in[5];
    const float* Wv  = (const float*)d_in[6];
    const float* Wff = (const float*)d_in[7];
    const float* bff = (const float*)d_in[8];
    const float* Wlm = (const float*)d_in[9];
    const float* blm = (const float*)d_in[10];
    float* out = (float*)d_out;
    char* ws = (char*)d_ws;

    hipLaunchKernelGGL(prep_kernel, dim3(264), dim3(256), 0, stream, Wk, Wq, Wv, Wff, Wlm, ws, out);
    hipLaunchKernelGGL(gpt_main, dim3(Bb), dim3(256), 0, stream,
                       idx, targets, tok_emb, pos_emb, bff, blm, (const char*)ws, out);
}

// Round 11
// 174.190 us; speedup vs baseline: 1.0627x; 1.0026x over previous
//
#include <hip/hip_runtime.h>
#include <hip/hip_bf16.h>

// Problem constants
#define Bb 2048
#define Tt 50
#define Vv 65
#define Ee 100
#define Hh 20
#define Dd 5

typedef __bf16 v8bf __attribute__((ext_vector_type(8)));
typedef short v8s __attribute__((ext_vector_type(8)));
typedef short v4s __attribute__((ext_vector_type(4)));
typedef float f32x4 __attribute__((ext_vector_type(4)));

__device__ __forceinline__ v8bf bzero8() {
    v8s z = {0, 0, 0, 0, 0, 0, 0, 0};
    union { v8s s; v8bf b; } u; u.s = z; return u.b;
}
__device__ __forceinline__ unsigned short bfbits(float f) {
    union { __hip_bfloat16 h; unsigned short s; } c;
    c.h = __float2bfloat16(f);
    return c.s;
}
__device__ __forceinline__ float bf2f(short s) {
    union { unsigned i; float f; } c; c.i = ((unsigned)(unsigned short)s) << 16; return c.f;
}
__device__ __forceinline__ unsigned pack2(float a, float b) {
    return (unsigned)bfbits(a) | ((unsigned)bfbits(b) << 16);
}

// K=16 bf16 MFMA (validated on HW in prior session)
__device__ __forceinline__ f32x4 mfma_16x16x16_bf16(v4s a, v4s b, f32x4 c) {
#if __has_builtin(__builtin_amdgcn_mfma_f32_16x16x16bf16_1k)
    return __builtin_amdgcn_mfma_f32_16x16x16bf16_1k(a, b, c, 0, 0, 0);
#else
    f32x4 d;
    asm volatile("v_mfma_f32_16x16x16_bf16 %0, %1, %2, %3\n\ts_nop 7\n\ts_nop 4"
                 : "=v"(d) : "v"(a), "v"(b), "v"(c));
    return d;
#endif
}

// ws layout (bytes)
#define WS_WKQV 1024                     // [320][128] bf16 (k rows pre-scaled by 10*log2e)
#define WS_WFF  (1024 + 81920)           // [128][128] bf16
#define WS_WLM  (1024 + 81920 + 32768)   // [80][128] bf16

#define XSTR 136                         // x/attn/h row stride (bf16 elems)
// shared overlays (bf16 element offsets into sh[21200] = 42.4 KB, 3 blocks/CU):
//  region1 @0     (8000): x[50][136] -> qb[20][50][8] -> attnbuf[50][136] -> lgl f32[50][68]
//  region2 @8000  (8000): kb[20][50][8] -> h[50][136]
//  region3 @16000 (5200): vtb[20][5][52]
// No bulk zeroing: weight pad COLUMNS (e>=100) are zeroed in prep, so finite
// garbage in A-pads multiplies 0.0. NaN sources cleared: x cols 100..127 in
// fill loop; qb AND kb d-pads in P2 pad-zero loop; vtb fully overwritten.
//
// LESSONS LEDGER (R1-R10 measured):
//  - (256,3) is the ONLY good launch bound (170-reg cap, never spilled).
//    (256,4) = 64arch+64acc -> spilled every attempt (R3/R7/R8). No hint ->
//    occ 21.7%, slowest. Occupancy tracks the hint, not resources. CLOSED.
//  - Single-pass P3 (serial shfl denominators): critical path grows (R2).
//  - SoA q/k, attn->vtb dump + scalar P4 reads: regressions (R4/R9).
//  - Cross-head qf/kf LOAD prefetch: neutral (R6).
//  - BATCHED MFMA issue (R10): +2us, MfmaUtil 11->15.3. ILP via explicit
//    bursts of independent ops WORKS at this occupancy.
//  - THIS round: extend bursts to the remaining serial clusters: braw[4]
//    hoisted to head start (LDS latency under t2s burst), esum[4][4] all
//    computed, then 4-wide ones-MFMA burst, then 16 rcps. Bit-identical.
//    Spill tripwire: FETCH ~1.555MB / WRITE ~26.1MB.
#define R2 8000
#define R3 16000
#define VSTR 52

__global__ __launch_bounds__(256) void prep_kernel(
    const float* __restrict__ Wk, const float* __restrict__ Wq,
    const float* __restrict__ Wv, const float* __restrict__ Wff,
    const float* __restrict__ Wlm, char* __restrict__ ws,
    float* __restrict__ out)
{
    int g = blockIdx.x * 256 + threadIdx.x;
    if (g == 0) out[Bb * Tt * Vv] = 0.f;   // loss slot; gpt_main atomicAdds into it
    __hip_bfloat16* wkqv = (__hip_bfloat16*)(ws + WS_WKQV);
    __hip_bfloat16* wff  = (__hip_bfloat16*)(ws + WS_WFF);
    __hip_bfloat16* wlm  = (__hip_bfloat16*)(ws + WS_WLM);
    if (g < 40960) {
        int n = g >> 7, e = g & 127;
        float v = 0.f;
        if (e < Ee) {
            if (n < 100)      v = Wk[n * Ee + e] * 14.4269504089f; // 10 * log2(e)
            else if (n < 200) v = Wq[(n - 100) * Ee + e];
            else if (n < 300) v = Wv[(n - 200) * Ee + e];
        }
        wkqv[g] = __float2bfloat16(v);
    } else if (g < 57344) {
        int gg = g - 40960; int n = gg >> 7, e = gg & 127;
        float v = (e < Ee && n < Ee) ? Wff[n * Ee + e] : 0.f;
        wff[gg] = __float2bfloat16(v);
    } else {
        int gg = g - 57344; int n = gg >> 7, e = gg & 127;
        float v = (e < Ee && n < Vv) ? Wlm[n * Ee + e] : 0.f;
        wlm[gg] = __float2bfloat16(v);
    }
}

__global__ __launch_bounds__(256, 3) void gpt_main(
    const int* __restrict__ idx, const int* __restrict__ targets,
    const float* __restrict__ tok_emb, const float* __restrict__ pos_emb,
    const float* __restrict__ b_ff, const float* __restrict__ b_lm,
    const char* __restrict__ ws, float* __restrict__ out)
{
    __shared__ __attribute__((aligned(16))) __hip_bfloat16 sh[21200];  // 42.4 KB
    __shared__ int tok_s[Tt];
    __shared__ float bsum;

    const int b    = blockIdx.x;
    const int tid  = threadIdx.x;
    const int wave = tid >> 6;
    const int ln   = tid & 15;
    const int quad = (tid >> 4) & 3;

    // ---- P1: stage idx; fill x = tok_emb[idx]+pos_emb (cols 100..127 zeroed) ----
    if (tid < Tt) tok_s[tid] = idx[b * Tt + tid];
    if (tid == 0) bsum = 0.f;
    __syncthreads();
    for (int i = tid; i < Tt * 32; i += 256) {
        int r = i >> 5, c4 = (i & 31) * 4;
        ushort4 o;
        if (c4 < Ee) {
            const float4 te = *(const float4*)&tok_emb[tok_s[r] * Ee + c4];
            const float4 pe = *(const float4*)&pos_emb[r * Ee + c4];
            o.x = bfbits(te.x + pe.x); o.y = bfbits(te.y + pe.y);
            o.z = bfbits(te.z + pe.z); o.w = bfbits(te.w + pe.w);
        } else {
            o.x = 0; o.y = 0; o.z = 0; o.w = 0;
        }
        *(ushort4*)&sh[r * XSTR + c4] = o;
    }
    __syncthreads();

    // ---- P2: kqv = x @ Wkqv^T via MFMA (4 waves x 5 n-tiles x 4 m-tiles) ----
    {
        const __hip_bfloat16* wkqv = (const __hip_bfloat16*)(ws + WS_WKQV);
        f32x4 acc[5][4];
#pragma unroll
        for (int j = 0; j < 5; ++j)
#pragma unroll
            for (int mt = 0; mt < 4; ++mt) {
                f32x4 z = {0.f, 0.f, 0.f, 0.f};
                acc[j][mt] = z;
            }
#pragma unroll
        for (int kt = 0; kt < 4; ++kt) {
            v8bf a[4];
#pragma unroll
            for (int mt = 0; mt < 4; ++mt)
                a[mt] = (mt < 3 || ln < 2)
                      ? *(const v8bf*)&sh[(mt * 16 + ln) * XSTR + kt * 32 + quad * 8]
                      : bzero8();
#pragma unroll
            for (int j = 0; j < 5; ++j) {
                int nt = wave * 5 + j;
                v8bf bfr = *(const v8bf*)&wkqv[(nt * 16 + ln) * 128 + kt * 32 + quad * 8];
#pragma unroll
                for (int mt = 0; mt < 4; ++mt)
                    acc[j][mt] = __builtin_amdgcn_mfma_f32_16x16x32_bf16(a[mt], bfr, acc[j][mt], 0, 0, 0);
            }
        }
        __syncthreads();   // all x reads done; region1 becomes qb
        // zero qb AND kb d-pads (elements 5..7 of each 8-elem row)
        for (int i = tid; i < 2000; i += 256) {
            int off = (i < 1000) ? i * 8 : R2 + (i - 1000) * 8;
            *(unsigned short*)&sh[off + 5] = 0;
            *(unsigned*)&sh[off + 6] = 0;
        }
        // C/D: col(n)=ln, row(m)=quad*4+r
#pragma unroll
        for (int j = 0; j < 5; ++j) {
            int n = (wave * 5 + j) * 16 + ln;
            if (n < 300) {
                int mat = n / 100;
                int jj  = n - mat * 100;
                int h   = jj / 5, d = jj - (jj / 5) * 5;
                if (mat == 2) {
                    // vtb: vectorized conflict-free stores, stride 52
                    int base = R3 + (h * 5 + d) * VSTR;
#pragma unroll
                    for (int mt = 0; mt < 4; ++mt) {
                        if (mt < 3 || quad == 0) {   // mt==3,quad>0 would spill past row end
                            float v0 = acc[j][mt][0], v1 = acc[j][mt][1];
                            float v2 = acc[j][mt][2], v3 = acc[j][mt][3];
                            if (mt == 3) { v2 = 0.f; v3 = 0.f; }   // t=50,51 pad slots stay zero
                            uint2 pk = make_uint2(pack2(v0, v1), pack2(v2, v3));
                            *(uint2*)&sh[base + mt * 16 + quad * 4] = pk;
                        }
                    }
                } else {
                    int roff = (mat == 0) ? R2 : 0;   // kb -> region2, qb -> region1
                    int rbase = h * 50;
#pragma unroll
                    for (int mt = 0; mt < 4; ++mt)
#pragma unroll
                        for (int r = 0; r < 4; ++r) {
                            int m = mt * 16 + quad * 4 + r;
                            if (m < Tt)
                                sh[roff + (rbase + m) * 8 + d] = __float2bfloat16(acc[j][mt][r]);
                        }
                }
            }
        }
    }
    __syncthreads();

    // ---- P3: attention, dual-orientation, full burst scheduling:
    //  braw[4] loads hoisted to head start (latency under t2s burst);
    //  t2s[10] QK burst; esum[4][4] all computed; 4-wide ones-MFMA burst;
    //  16 rcps; then PV with per-ms t1 bursts. Bit-identical math. ----
    unsigned attp[5][8];
    {
        const float BIGF = 3.0e38f;
        float dA2[4], dA1[4], d50[4];
#pragma unroll
        for (int r = 0; r < 4; ++r) {
            int qr = quad * 4 + r;
            dA2[r] = (qr >= ln) ? BIGF : 0.f;   // orient-2 diag tiles: t>=s
            dA1[r] = (ln >= qr) ? BIGF : 0.f;   // orient-1 diag tiles (u==0): t>=s
            d50[r] = (qr < 2)  ? BIGF : 0.f;    // tile-3 reg mask: (48+qr)<50
        }
        const float tl3 = (ln < 2) ? BIGF : 0.f;  // orient-1 t-tile 3: t=48+ln<50

        v4s ones4; ones4[0] = ones4[1] = ones4[2] = ones4[3] = (short)0x3F80; // bf16 1.0

#pragma unroll
        for (int hj = 0; hj < 5; ++hj) {
            const int h = wave * 5 + hj;
            v8bf qf[4], kf[4];
#pragma unroll
            for (int i = 0; i < 4; ++i) {
                int row = (h * 50 + i * 16 + ln) * 8;
                qf[i] = (quad == 0) ? *(const v8bf*)&sh[row] : bzero8();
                kf[i] = (quad == 0) ? *(const v8bf*)&sh[R2 + row] : bzero8();
            }
            // --- braw batch: all 4 v-column loads issued up-front ---
            v4s braw[4];
#pragma unroll
            for (int ms = 0; ms < 4; ++ms) {
                if (ln < Dd && (ms < 3 || quad == 0))
                    braw[ms] = *(const v4s*)&sh[R3 + (h * 5 + ln) * VSTR + ms * 16 + quad * 4];
                else { v4s zz = {0, 0, 0, 0}; braw[ms] = zz; }
            }
            // --- orient-2 QK burst: 10 independent MFMAs (ns,mt>=ns) ---
            f32x4 t2s[10];
            {
                int idx = 0;
#pragma unroll
                for (int ns = 0; ns < 4; ++ns)
#pragma unroll
                    for (int mt = 0; mt < 4; ++mt)
                        if (mt >= ns) {
                            f32x4 z = {0.f, 0.f, 0.f, 0.f};
                            t2s[idx++] = __builtin_amdgcn_mfma_f32_16x16x32_bf16(kf[mt], qf[ns], z, 0, 0, 0);
                        }
            }
            // --- all esums (exp bursts), then ones-MFMA burst, then rcp batch ---
            float esum[4][4];
            {
                int idx = 0;
#pragma unroll
                for (int ns = 0; ns < 4; ++ns) {
#pragma unroll
                    for (int r = 0; r < 4; ++r) esum[ns][r] = 0.f;
#pragma unroll
                    for (int mt = 0; mt < 4; ++mt)
                        if (mt >= ns) {
                            f32x4 t2 = t2s[idx++];
#pragma unroll
                            for (int r = 0; r < 4; ++r) {
                                float x = __builtin_amdgcn_exp2f(t2[r]);
                                if (mt == ns) x = fminf(x, dA2[r]);   // causal mask, diag tile
                                if (mt == 3)  x = fminf(x, d50[r]);   // t<50, last t-tile
                                esum[ns][r] += x;
                            }
                        }
                }
            }
            f32x4 dres[4];
#pragma unroll
            for (int ns = 0; ns < 4; ++ns) {
                v4s af0;
                af0[0] = (short)bfbits(esum[ns][0]); af0[1] = (short)bfbits(esum[ns][1]);
                af0[2] = (short)bfbits(esum[ns][2]); af0[3] = (short)bfbits(esum[ns][3]);
                f32x4 z0 = {0.f, 0.f, 0.f, 0.f};
                dres[ns] = mfma_16x16x16_bf16(af0, ones4, z0);
            }
            float rdv[4][4];
#pragma unroll
            for (int ns = 0; ns < 4; ++ns)
#pragma unroll
                for (int r = 0; r < 4; ++r)
                    rdv[ns][r] = (ns < 3 || (quad * 4 + r) < 2)   // s<50 guard (select: NaN-proof)
                               ? __builtin_amdgcn_rcpf(dres[ns][r]) : 0.f;
            // --- PV (orient-1), t1 batched within each ms ---
            f32x4 pac[4];
#pragma unroll
            for (int mt = 0; mt < 4; ++mt) { f32x4 z = {0.f, 0.f, 0.f, 0.f}; pac[mt] = z; }
#pragma unroll
            for (int ms = 0; ms < 4; ++ms) {
                v4s bvt;
#pragma unroll
                for (int j = 0; j < 4; ++j)
                    bvt[j] = (short)bfbits(bf2f(braw[ms][j]) * rdv[ms][j]);
                // t1 burst: independent MFMAs for u = 0..3-ms
                f32x4 t1s[4];
#pragma unroll
                for (int u = 0; u < 4; ++u)
                    if (u < 4 - ms) {
                        f32x4 z = {0.f, 0.f, 0.f, 0.f};
                        t1s[u] = __builtin_amdgcn_mfma_f32_16x16x32_bf16(qf[ms], kf[ms + u], z, 0, 0, 0);
                    }
#pragma unroll
                for (int u = 0; u < 4; ++u)
                    if (u < 4 - ms) {
                        v4s af;
#pragma unroll
                        for (int r = 0; r < 4; ++r) {
                            float x = __builtin_amdgcn_exp2f(t1s[u][r]);
                            if (u == 0)      x = fminf(x, dA1[r]);   // causal mask, diag tile
                            if (ms + u == 3) x = fminf(x, tl3);      // t<50, last t-tile
                            if (ms == 3)     x = fminf(x, d50[r]);   // s<50, last s-tile
                            af[r] = (short)bfbits(x);
                        }
                        pac[ms + u] = mfma_16x16x16_bf16(af, bvt, pac[ms + u]);
                    }
            }
            // C/D of 16x16x16: col n=ln (d), row m=quad*4+r -> t = mt*16+quad*4+r
#pragma unroll
            for (int mt = 0; mt < 4; ++mt) {
                attp[hj][mt * 2]     = pack2(pac[mt][0], pac[mt][1]);
                attp[hj][mt * 2 + 1] = pack2(pac[mt][2], pac[mt][3]);
            }
        }
    }
    __syncthreads();   // all qb/kb/vtb reads done; region1 becomes attnbuf

    // ---- dump attn registers -> attnbuf (region1, [50][136]) ----
#pragma unroll
    for (int hj = 0; hj < 5; ++hj) {
        int col = (wave * 5 + hj) * 5 + ln;
#pragma unroll
        for (int mt = 0; mt < 4; ++mt)
#pragma unroll
            for (int r = 0; r < 4; ++r) {
                int t = mt * 16 + quad * 4 + r;
                if (ln < Dd && t < Tt) {
                    unsigned w = attp[hj][mt * 2 + (r >> 1)];
                    unsigned short v = (unsigned short)((r & 1) ? (w >> 16) : (w & 0xffff));
                    *(unsigned short*)&sh[t * XSTR + col] = v;
                }
            }
    }
    __syncthreads();

    // ---- P4: h = relu(attn @ Wff^T + b_ff); attnbuf(region1) -> h(region2) ----
    {
        const __hip_bfloat16* wff = (const __hip_bfloat16*)(ws + WS_WFF);
        f32x4 fac[2][4];
#pragma unroll
        for (int u = 0; u < 2; ++u)
#pragma unroll
            for (int mt = 0; mt < 4; ++mt) {
                f32x4 z = {0.f, 0.f, 0.f, 0.f};
                fac[u][mt] = z;
            }
        const int nn = (wave < 3) ? 2 : 1;
#pragma unroll
        for (int kt = 0; kt < 4; ++kt) {
            v8bf a[4];
#pragma unroll
            for (int mt = 0; mt < 4; ++mt)
                a[mt] = (mt < 3 || ln < 2)
                      ? *(const v8bf*)&sh[(mt * 16 + ln) * XSTR + kt * 32 + quad * 8]
                      : bzero8();
#pragma unroll
            for (int u = 0; u < 2; ++u) {
                if (u < nn) {
                    int nt = wave + u * 4;
                    v8bf bfr = *(const v8bf*)&wff[(nt * 16 + ln) * 128 + kt * 32 + quad * 8];
#pragma unroll
                    for (int mt = 0; mt < 4; ++mt)
                        fac[u][mt] = __builtin_amdgcn_mfma_f32_16x16x32_bf16(a[mt], bfr, fac[u][mt], 0, 0, 0);
                }
            }
        }
#pragma unroll
        for (int u = 0; u < 2; ++u) {
            if (u < nn) {
                int n = (wave + u * 4) * 16 + ln;
                if (n < Ee) {
                    float bias = b_ff[n];
#pragma unroll
                    for (int mt = 0; mt < 4; ++mt)
#pragma unroll
                        for (int r = 0; r < 4; ++r) {
                            int m = mt * 16 + quad * 4 + r;
                            if (m < Tt) {
                                float v = fac[u][mt][r] + bias;
                                sh[R2 + m * XSTR + n] = __float2bfloat16(v > 0.f ? v : 0.f);
                            }
                        }
                }
            }
        }
    }
    __syncthreads();

    // ---- P5: logits = h @ Wlm^T + b_lm; h(region2) -> out + logits f32(region1) ----
    {
        const __hip_bfloat16* wlm = (const __hip_bfloat16*)(ws + WS_WLM);
        float* lgl = (float*)sh;   // [50][68] f32 = 13600B
#pragma unroll
        for (int i = 0; i < 5; ++i) {
            int job = wave + i * 4;            // 0..19
            int mt = job / 5, nt = job - (job / 5) * 5;
            f32x4 acc = {0.f, 0.f, 0.f, 0.f};
#pragma unroll
            for (int kt = 0; kt < 4; ++kt) {
                v8bf a = (mt < 3 || ln < 2)
                       ? *(const v8bf*)&sh[R2 + (mt * 16 + ln) * XSTR + kt * 32 + quad * 8]
                       : bzero8();
                v8bf bf = *(const v8bf*)&wlm[(nt * 16 + ln) * 128 + kt * 32 + quad * 8];
                acc = __builtin_amdgcn_mfma_f32_16x16x32_bf16(a, bf, acc, 0, 0, 0);
            }
            int n = nt * 16 + ln;
            if (n < Vv) {
                float bias = b_lm[n];
#pragma unroll
                for (int r = 0; r < 4; ++r) {
                    int m = mt * 16 + quad * 4 + r;
                    if (m < Tt) {
                        float v = acc[r] + bias;
                        out[(b * Tt + m) * Vv + n] = v;
                        lgl[m * 68 + n] = v;
                    }
                }
            }
        }
    }
    __syncthreads();

    // ---- P6: loss; 4 lanes per token row; one device atomic per block ----
    if (tid < 200) {
        int r = tid >> 2, lv = tid & 3;
        const float* row = (const float*)sh + r * 68;
        float mx = -3.0e38f;
        for (int v = lv; v < Vv; v += 4) mx = fmaxf(mx, row[v]);
        mx = fmaxf(mx, __shfl_xor(mx, 1));
        mx = fmaxf(mx, __shfl_xor(mx, 2));
        float sum = 0.f;
        for (int v = lv; v < Vv; v += 4)
            sum += __builtin_amdgcn_exp2f((row[v] - mx) * 1.4426950408889634f);
        sum += __shfl_xor(sum, 1);
        sum += __shfl_xor(sum, 2);
        if (lv == 0) {
            float lse = mx + 0.69314718055994531f * log2f(sum);
            int tgt = targets[b * Tt + r];
            atomicAdd(&bsum, lse - row[tgt]);
        }
    }
    __syncthreads();
    if (tid == 0)
        atomicAdd(&out[Bb * Tt * Vv], bsum * (1.0f / (float)(Bb * Tt)));
}

extern "C" void kernel_launch(void* const* d_in, const int* in_sizes, int n_in,
                              void* d_out, int out_size, void* d_ws, size_t ws_size,
                              hipStream_t stream)
{
    const int* idx     = (const int*)d_in[0];
    const int* targets = (const int*)d_in[1];
    const float* tok_emb = (const float*)d_in[2];
    const float* pos_emb = (const float*)d_in[3];
    const float* Wk  = (const float*)d_in[4];
    const float* Wq  = (const float*)d_in[5];
    const float* Wv  = (const float*)d_in[6];
    const float* Wff = (const float*)d_in[7];
    const float* bff = (const float*)d_in[8];
    const float* Wlm = (const float*)d_in[9];
    const float* blm = (const float*)d_in[10];
    float* out = (float*)d_out;
    char* ws = (char*)d_ws;

    hipLaunchKernelGGL(prep_kernel, dim3(264), dim3(256), 0, stream, Wk, Wq, Wv, Wff, Wlm, ws, out);
    hipLaunchKernelGGL(gpt_main, dim3(Bb), dim3(256), 0, stream,
                       idx, targets, tok_emb, pos_emb, bff, blm, (const char*)ws, out);
}